// Round 14
// baseline (116.744 us; speedup 1.0000x reference)
//
#include <hip/hip_runtime.h>

#define NPTS 8192
#define BATCH 4
#define BLOCK 256
#define NF 8                    // query tiles (A-frags) per wave
#define QPW (NF * 16)           // 128 queries per wave
#define QPB (QPW * 4)           // 512 queries per block
#define QBLOCKS (NPTS / QPB)    // 16
#define SEGS 16
#define SEG_SHIFT 4
#define SEGLEN (NPTS / SEGS)    // 512 targets per segment

typedef short bf16x8 __attribute__((ext_vector_type(8)));
typedef float f32x4 __attribute__((ext_vector_type(4)));

// fp32 -> bf16 bits (RNE) and back
__device__ inline short f2bf(float v) {
    unsigned u = __float_as_uint(v);
    u += 0x7FFFu + ((u >> 16) & 1u);
    return (short)(u >> 16);
}
__device__ inline float bf2f(short h) {
    return __uint_as_float(((unsigned)(unsigned short)h) << 16);
}

// ---------------------------------------------------------------------------
// MFMA chamfer. d(p,q) = |p|^2 + (|q|^2 - 2 p.q); the parenthesized part is
// one 16x16x32 bf16 MFMA contraction with split-precision K-slots:
//   k0-2 : A=-2p_h      B=q_h
//   k3-5 : A=-2p_l      B=q_h
//   k6-8 : A=-2p_h      B=q_l
//   k9   : A=1          B=sq_h
//   k10  : A=1          B=sq_l      (k11..31 zero)
// Residual error ~ p_l.q_l ~ 5e-5 << 3.46 threshold. A/B frags are built
// with the SAME (lane-group, j) slotting, so the result is invariant to the
// ISA's internal k permutation. C/D: col=lane&15 (target n), row=
// (lane>>4)*4+reg (query m) — the m89-verified mapping. Running min kept
// per C-reg across target tiles; cross-lane (over n) reduction at the end.
// |p|^2 added in fp32, clamped >=0, merged via atomicMin on float bits
// (mins pre-set to 0xFFFFFFFF by memset). Block (0,0,0) zeroes out[0].
// ---------------------------------------------------------------------------
__global__ __launch_bounds__(256) void chamfer_kernel(
    const float* __restrict__ x, const float* __restrict__ y,
    unsigned* __restrict__ mins, float* __restrict__ out) {
    // Bform halves: [0..SEGLEN): k0-7 = {qhx,qhy,qhz,qhx,qhy,qhz,qlx,qly}
    //               [SEGLEN..2*SEGLEN): k8-15 = {qlz,sqh,sql,0,...}
    __shared__ bf16x8 ldsB[2 * SEGLEN];  // 16 KB

    if (blockIdx.x == 0 && blockIdx.y == 0 && blockIdx.z == 0 && threadIdx.x == 0)
        out[0] = 0.0f;

    const int dir = blockIdx.z;
    const int b = blockIdx.y;
    const int seg = blockIdx.x & (SEGS - 1);
    const int qb = blockIdx.x >> SEG_SHIFT;

    const float* pts = dir ? y : x;  // query set
    const float* oth = dir ? x : y;  // target set

    // ---- stage target segment into LDS in Bform (2 targets per thread) ----
    for (int p = threadIdx.x; p < SEGLEN; p += BLOCK) {
        const float* q = oth + ((size_t)b * NPTS + seg * SEGLEN + p) * 3;
        const float qx = q[0], qy = q[1], qz = q[2];
        const float sq = fmaf(qz, qz, fmaf(qy, qy, qx * qx));
        const short qhx = f2bf(qx), qhy = f2bf(qy), qhz = f2bf(qz);
        const short qlx = f2bf(qx - bf2f(qhx));
        const short qly = f2bf(qy - bf2f(qhy));
        const short qlz = f2bf(qz - bf2f(qhz));
        const short sqh = f2bf(sq);
        const short sql = f2bf(sq - bf2f(sqh));
        bf16x8 b0, b1;
        b0[0] = qhx; b0[1] = qhy; b0[2] = qhz;
        b0[3] = qhx; b0[4] = qhy; b0[5] = qhz;
        b0[6] = qlx; b0[7] = qly;
        b1[0] = qlz; b1[1] = sqh; b1[2] = sql;
        b1[3] = 0; b1[4] = 0; b1[5] = 0; b1[6] = 0; b1[7] = 0;
        ldsB[p] = b0;
        ldsB[SEGLEN + p] = b1;
    }

    // ---- build A-frags (queries) in registers ----
    const int lane = threadIdx.x & 63;
    const int wv = threadIdx.x >> 6;       // wave 0..3
    const int n = lane & 15;               // tile-local index
    const int g = lane >> 4;               // k lane-group 0..3
    const int qbase = qb * QPB + wv * QPW; // this wave's first query

    bf16x8 afrag[NF];
    float sp[NF];
    float best[NF][4];
    const short one = f2bf(1.0f);
#pragma unroll
    for (int f = 0; f < NF; ++f) {
        const int qi = qbase + f * 16 + n;
        const float* p = pts + ((size_t)b * NPTS + qi) * 3;
        const float px = p[0], py = p[1], pz = p[2];
        sp[f] = fmaf(pz, pz, fmaf(py, py, px * px));
        const short phx = f2bf(px), phy = f2bf(py), phz = f2bf(pz);
        bf16x8 a;
#pragma unroll
        for (int i = 0; i < 8; ++i) a[i] = 0;
        if (g == 0) {
            a[0] = f2bf(-2.0f * bf2f(phx));
            a[1] = f2bf(-2.0f * bf2f(phy));
            a[2] = f2bf(-2.0f * bf2f(phz));
            a[3] = f2bf(-2.0f * (px - bf2f(phx)));
            a[4] = f2bf(-2.0f * (py - bf2f(phy)));
            a[5] = f2bf(-2.0f * (pz - bf2f(phz)));
            a[6] = f2bf(-2.0f * bf2f(phx));
            a[7] = f2bf(-2.0f * bf2f(phy));
        } else if (g == 1) {
            a[0] = f2bf(-2.0f * bf2f(phz));
            a[1] = one;
            a[2] = one;
        }
        afrag[f] = a;
        best[f][0] = best[f][1] = best[f][2] = best[f][3] = 3.0e38f;
    }

    __syncthreads();

    // ---- main loop: 2 target tiles per iteration ----
    const f32x4 zero4 = {0.0f, 0.0f, 0.0f, 0.0f};
    bf16x8 bz;
#pragma unroll
    for (int i = 0; i < 8; ++i) bz[i] = 0;

    for (int t = 0; t < SEGLEN / 16; t += 2) {
        bf16x8 bvA = bz, bvB = bz;
        if (g < 2) {
            bvA = ldsB[g * SEGLEN + t * 16 + n];
            bvB = ldsB[g * SEGLEN + (t + 1) * 16 + n];
        }
#pragma unroll
        for (int f = 0; f < NF; ++f) {
            const f32x4 cA = __builtin_amdgcn_mfma_f32_16x16x32_bf16(
                afrag[f], bvA, zero4, 0, 0, 0);
            const f32x4 cB = __builtin_amdgcn_mfma_f32_16x16x32_bf16(
                afrag[f], bvB, zero4, 0, 0, 0);
#pragma unroll
            for (int r = 0; r < 4; ++r)
                best[f][r] = fminf(fminf(best[f][r], cA[r]), cB[r]);  // v_min3
        }
    }

    // ---- epilogue: reduce over cols (n) cross-lane, add |p|^2, atomicMin ----
    unsigned* om = mins + (size_t)(dir * BATCH + b) * NPTS;
#pragma unroll
    for (int f = 0; f < NF; ++f) {
#pragma unroll
        for (int r = 0; r < 4; ++r) {
            float v = best[f][r];
            v = fminf(v, __shfl_xor(v, 1, 64));
            v = fminf(v, __shfl_xor(v, 2, 64));
            v = fminf(v, __shfl_xor(v, 4, 64));
            v = fminf(v, __shfl_xor(v, 8, 64));
            // this lane now has the min for query row m = g*4 + r of frag f;
            // fetch that query's |p|^2 from the lane that loaded it (group 0)
            const int m = g * 4 + r;
            const float spq = __shfl(sp[f], m, 64);
            if (n == 0) {
                const float d = fmaxf(spq + v, 0.0f);
                atomicMin(&om[qbase + f * 16 + m], __float_as_uint(d));
            }
        }
    }
}

// ---------------------------------------------------------------------------
// finalize: 64 blocks x 256 threads (R7-R13 proven). Each block sums a 4 KB
// slice of mins (uint4, coalesced), reduces, atomicAdds partial * 1/(B*N)
// into out[0] (zeroed by chamfer block 0). gid 0 adds the regularizer.
// ---------------------------------------------------------------------------
__global__ __launch_bounds__(256) void finalize_kernel(
    const unsigned* __restrict__ mins, const float* __restrict__ R,
    const float* __restrict__ S, const float* __restrict__ t,
    const float* __restrict__ R_gt, const float* __restrict__ S_gt,
    const float* __restrict__ t_gt, float* __restrict__ out) {
    const uint4* m4 = (const uint4*)mins;  // 2*B*N/4 = 16384 uint4s
    const int gid = blockIdx.x * 256 + (int)threadIdx.x;
    const uint4 u = m4[gid];
    float v = (__uint_as_float(u.x) + __uint_as_float(u.y) +
               __uint_as_float(u.z) + __uint_as_float(u.w)) *
              (1.0f / (BATCH * NPTS));

    if (gid == 0) {
        float acc = 0.0f;
        for (int b = 0; b < BATCH; ++b)
            for (int i = 0; i < 3; ++i)
                for (int k = 0; k < 3; ++k) {
                    float s = 0.0f;
                    for (int j = 0; j < 3; ++j)
                        s += R_gt[b * 9 + j * 3 + i] * R[b * 9 + j * 3 + k];
                    s -= (i == k) ? 1.0f : 0.0f;
                    acc += s * s;
                }
        for (int d = 0; d < 3; ++d)  // jnp.diagonal(S, axis1=0, axis2=1)
            for (int a = 0; a < 3; ++a) {
                const float diff = S[d * 9 + d * 3 + a] - S_gt[d * 9 + d * 3 + a];
                acc += diff * diff;
            }
        for (int b = 0; b < BATCH; ++b)
            for (int k = 0; k < 3; ++k) {
                const float diff = t[b * 3 + k] - t_gt[b * 3 + k];
                acc += diff * diff;
            }
        v += acc;
    }

    for (int off = 32; off; off >>= 1) v += __shfl_down(v, off, 64);
    __shared__ float wsum[4];
    const int lane = threadIdx.x & 63;
    const int wave = threadIdx.x >> 6;
    if (lane == 0) wsum[wave] = v;
    __syncthreads();
    if (wave == 0) {
        v = (lane < 4) ? wsum[lane] : 0.0f;
        for (int off = 2; off; off >>= 1) v += __shfl_down(v, off, 64);
        if (lane == 0) atomicAdd(out, v);
    }
}

extern "C" void kernel_launch(void* const* d_in, const int* in_sizes, int n_in,
                              void* d_out, int out_size, void* d_ws, size_t ws_size,
                              hipStream_t stream) {
    const float* x    = (const float*)d_in[0];
    const float* y    = (const float*)d_in[1];
    const float* R    = (const float*)d_in[2];
    const float* S    = (const float*)d_in[3];
    const float* t    = (const float*)d_in[4];
    const float* R_gt = (const float*)d_in[5];
    const float* S_gt = (const float*)d_in[6];
    const float* t_gt = (const float*)d_in[7];
    float* out = (float*)d_out;
    unsigned* mins = (unsigned*)d_ws;  // 2*B*N uints = 256 KiB

    hipMemsetAsync(mins, 0xFF, (size_t)2 * BATCH * NPTS * sizeof(unsigned), stream);

    chamfer_kernel<<<dim3(QBLOCKS * SEGS, BATCH, 2), dim3(BLOCK), 0, stream>>>(
        x, y, mins, out);

    finalize_kernel<<<dim3(2 * BATCH * NPTS / 4 / 256), dim3(BLOCK), 0, stream>>>(
        mins, R, S, t, R_gt, S_gt, t_gt, out);
}